// Round 3
// baseline (153.685 us; speedup 1.0000x reference)
//
#include <hip/hip_runtime.h>
#include <hip/hip_bf16.h>

// B=32 L=1024 D=128 H=128 W=9 F=137. Output f32 (32,1024,128).
// ws: W12Bt bf16[256][128] @0 (64KB); CwBt bf16[128][1152] @65536 (288KB).
// mega: 512 blocks x 512 thr, 64 output rows each. LDS 69008B (2 blocks/CU):
//   E   @0      uint4[80*16] : emb rows l0-4..l0+67 bf16, XOR-swizzled granules
//   Hs  @20480  bf16[2][80][128] : K-prescaled f,g (XOR by (row>>2)&3 on h-bit4/5)
//   pwL @61440  f32[9][128] : K*(w2_pos[w]+w2b+w1_pos+w1b)
//   vwL @66048  f32[128]
//   wtT @66560  f32[9][68]  : softmax weights, [w][row] padded stride
// tanh(x) = 1-2*rcp(1+exp2(K*x)), K=2*log2(e); Sum_h vw const cancels in softmax.

typedef __attribute__((ext_vector_type(8))) short bf16x8;
typedef __attribute__((ext_vector_type(4))) float f32x4;

#define LL 1024
#define TANHK 2.885390081777927f

__device__ __forceinline__ unsigned short f2bf(float f) {
  unsigned int u = __float_as_uint(f);
  u = u + 0x7FFFu + ((u >> 16) & 1u);   // RNE
  return (unsigned short)(u >> 16);
}
__device__ __forceinline__ float bf2f(unsigned short us) {
  return __uint_as_float(((unsigned int)us) << 16);
}

// ---------- prep: bf16 K-contiguous weight copies (proven) ----------
__global__ __launch_bounds__(256) void prep_kernel(
    const float* __restrict__ w1, const float* __restrict__ w2,
    const float* __restrict__ cnn,
    unsigned short* __restrict__ W12Bt, unsigned short* __restrict__ CwBt) {
  int gid = blockIdx.x * 256 + threadIdx.x;
  if (blockIdx.x < 128) {            // 32768: W12Bt[n][d]  (n<128: w1 col, else w2 col)
    int n = gid >> 7, d = gid & 127;
    float v = (n < 128) ? w1[d * 128 + n] : w2[d * 128 + (n - 128)];
    W12Bt[n * 128 + d] = f2bf(v);
  } else {                           // 147456: CwBt[h][w*128+d]
    int idx = gid - 32768;
    int h = idx / 1152;
    int c = idx - h * 1152;
    int w = c >> 7, d = c & 127;
    CwBt[h * 1152 + c] = f2bf(cnn[(w * 137 + d) * 128 + h]);
  }
}

// ---------- mega ----------
__global__ __launch_bounds__(512, 4) void mega_kernel(
    const float* __restrict__ emb,
    const unsigned short* __restrict__ W12Bt,
    const unsigned short* __restrict__ CwBt,
    const float* __restrict__ w1, const float* __restrict__ w1b,
    const float* __restrict__ w2, const float* __restrict__ w2b,
    const float* __restrict__ vw,
    const float* __restrict__ cnn, const float* __restrict__ cnnb,
    float* __restrict__ out) {
  extern __shared__ __align__(16) unsigned char smem[];
  uint4* E            = (uint4*)smem;                       // 20480
  unsigned short* Hs  = (unsigned short*)(smem + 20480);    // 40960
  float* pwL          = (float*)(smem + 61440);             // 4608
  float* vwL          = (float*)(smem + 66048);             // 512
  float* wtT          = (float*)(smem + 66560);             // 2448

  int tid = threadIdx.x;
  int bid = blockIdx.x;
  int b = bid >> 4, l0 = (bid & 15) << 6;
  int lane = tid & 63, wid = tid >> 6;
  int l15 = lane & 15, l4 = lane >> 4;

  // ---- phase 0: stage E (80 rows: 72 real + 8 zero-pad), pwL, vwL ----
  #pragma unroll
  for (int s = 0; s < 5; ++s) {
    int i = tid + s * 512;
    if (i < 1280) {
      int er = i >> 4, g = i & 15;
      int t = l0 + er - 4;
      uint4 v = {0u, 0u, 0u, 0u};
      if (er < 72 && t >= 0 && t < LL) {
        const float4* src = (const float4*)(emb + ((size_t)(b * LL + t) << 7) + g * 8);
        float4 x0 = src[0], x1 = src[1];
        v.x = f2bf(x0.x) | ((unsigned)f2bf(x0.y) << 16);
        v.y = f2bf(x0.z) | ((unsigned)f2bf(x0.w) << 16);
        v.z = f2bf(x1.x) | ((unsigned)f2bf(x1.y) << 16);
        v.w = f2bf(x1.z) | ((unsigned)f2bf(x1.w) << 16);
      }
      E[er * 16 + (g ^ (er & 7))] = v;
    } else if (i < 2432) {
      int idx = i - 1280;
      int w = idx >> 7, h = idx & 127;
      pwL[idx] = TANHK * (w2[(128 + w) * 128 + h] + w2b[h] +
                          w1[132 * 128 + h] + w1b[h]);
    } else {
      int h = i - 2432;
      vwL[h] = vw[h];
    }
  }
  __syncthreads();

  // ---- phase 2: Hs[part][i] = K * (E_i @ w{1,2}d), B-frags straight from L2 ----
  const bf16x8* Eb = (const bf16x8*)E;
  #pragma unroll
  for (int jj = 0; jj < 2; ++jj) {
    int job = wid + jj * 8;
    if (job < 10) {
      int part = job >= 5;
      int er0 = (job - part * 5) * 16;
      f32x4 acc[8];
      #pragma unroll
      for (int nn = 0; nn < 8; ++nn) acc[nn] = (f32x4){0.f, 0.f, 0.f, 0.f};
      #pragma unroll
      for (int kk = 0; kk < 4; ++kk) {
        int gk = kk * 4 + l4;
        int er = er0 + l15;
        bf16x8 aF = Eb[er * 16 + (gk ^ (er & 7))];
        #pragma unroll
        for (int nn = 0; nn < 8; ++nn) {
          bf16x8 bF = *(const bf16x8*)(W12Bt +
              (size_t)((part << 7) + nn * 16 + l15) * 128 + gk * 8);
          acc[nn] = __builtin_amdgcn_mfma_f32_16x16x32_bf16(aF, bF, acc[nn], 0, 0, 0);
        }
      }
      unsigned short* Hp = Hs + part * 10240;
      #pragma unroll
      for (int nn = 0; nn < 8; ++nn)
        #pragma unroll
        for (int j = 0; j < 4; ++j) {
          int i2 = er0 + l4 * 4 + j;
          Hp[i2 * 128 + ((nn * 16 + l15) ^ (l4 << 4))] = f2bf(TANHK * acc[nn][j]);
        }
    }
  }
  __syncthreads();

  // ---- phase 3: scores + softmax; 4 rows per pass (16-lane groups) ----
  {
    int q = lane >> 4, u = lane & 15, u8 = u * 8;
    const unsigned short* Hs1 = Hs;
    const unsigned short* Hs2 = Hs + 10240;
    #pragma unroll
    for (int pass = 0; pass < 2; ++pass) {
      int r = wid * 8 + pass * 4 + q;
      int fi = r + 4;
      int fxor = ((fi >> 2) & 3) << 4;
      bf16x8 fraw = *(const bf16x8*)&Hs1[fi * 128 + (u8 ^ fxor)];
      float fr[8];
      #pragma unroll
      for (int j = 0; j < 8; ++j) fr[j] = bf2f((unsigned short)fraw[j]);
      f32x4 vr0 = *(const f32x4*)&vwL[u8];
      f32x4 vr1 = *(const f32x4*)&vwL[u8 + 4];
      float sc[9];
      #pragma unroll
      for (int w = 0; w < 9; ++w) {
        int gi = r + w;
        int gxor = ((gi >> 2) & 3) << 4;
        bf16x8 graw = *(const bf16x8*)&Hs2[gi * 128 + (u8 ^ gxor)];
        f32x4 pw0 = *(const f32x4*)&pwL[w * 128 + u8];
        f32x4 pw1 = *(const f32x4*)&pwL[w * 128 + u8 + 4];
        float a = 0.f;
        #pragma unroll
        for (int j = 0; j < 4; ++j) {
          float e = exp2f(fr[j] + bf2f((unsigned short)graw[j]) + pw0[j]);
          a = fmaf(vr0[j], __builtin_amdgcn_rcpf(1.f + e), a);
        }
        #pragma unroll
        for (int j = 0; j < 4; ++j) {
          float e = exp2f(fr[4 + j] + bf2f((unsigned short)graw[4 + j]) + pw1[j]);
          a = fmaf(vr1[j], __builtin_amdgcn_rcpf(1.f + e), a);
        }
        a += __shfl_xor(a, 1, 64);
        a += __shfl_xor(a, 2, 64);
        a += __shfl_xor(a, 4, 64);
        a += __shfl_xor(a, 8, 64);
        sc[w] = a;              // score = -2*sc (+const): min sc == max score
      }
      float mn = sc[0];
      #pragma unroll
      for (int w = 1; w < 9; ++w) mn = fminf(mn, sc[w]);
      float p[9], sum = 0.f;
      #pragma unroll
      for (int w = 0; w < 9; ++w) { p[w] = exp2f(TANHK * (mn - sc[w])); sum += p[w]; }
      float inv = __builtin_amdgcn_rcpf(sum);
      if (u < 9) {
        float wv = p[0];
        #pragma unroll
        for (int w = 1; w < 9; ++w) wv = (u == w) ? p[w] : wv;
        wtT[u * 68 + r] = wv * inv;
      }
    }
  }
  __syncthreads();

  // ---- phase 4: out-GEMM; A from E (unscaled), B from L2, no barriers ----
  int wr = wid >> 2, wc = wid & 3;     // 32 rows x 32 h per wave
  int h0 = wc * 32 + l15;
  f32x4 fin[2][2];
  #pragma unroll
  for (int m = 0; m < 2; ++m)
    #pragma unroll
    for (int n = 0; n < 2; ++n) fin[m][n] = (f32x4){0.f, 0.f, 0.f, 0.f};
  #pragma unroll
  for (int w = 0; w < 9; ++w) {
    f32x4 tmp[2][2];
    #pragma unroll
    for (int m = 0; m < 2; ++m)
      #pragma unroll
      for (int n = 0; n < 2; ++n) tmp[m][n] = (f32x4){0.f, 0.f, 0.f, 0.f};
    #pragma unroll
    for (int kk = 0; kk < 4; ++kk) {
      int gk = kk * 4 + l4;
      bf16x8 aF[2];
      #pragma unroll
      for (int m = 0; m < 2; ++m) {
        int er = wr * 32 + m * 16 + l15 + w;
        aF[m] = Eb[er * 16 + (gk ^ (er & 7))];
      }
      #pragma unroll
      for (int n = 0; n < 2; ++n) {
        int hh = wc * 32 + n * 16 + l15;
        bf16x8 bF = *(const bf16x8*)(CwBt + (size_t)hh * 1152 + w * 128 + gk * 8);
        #pragma unroll
        for (int m = 0; m < 2; ++m)
          tmp[m][n] = __builtin_amdgcn_mfma_f32_16x16x32_bf16(aF[m], bF, tmp[m][n], 0, 0, 0);
      }
    }
    float cp0 = cnn[(w * 138 + 128) * 128 + h0];
    float cp1 = cnn[(w * 138 + 128) * 128 + h0 + 16];
    #pragma unroll
    for (int m = 0; m < 2; ++m) {
      f32x4 wt4 = *(const f32x4*)&wtT[w * 68 + wr * 32 + m * 16 + l4 * 4];
      #pragma unroll
      for (int j = 0; j < 4; ++j) {
        fin[m][0][j] += wt4[j] * (tmp[m][0][j] + cp0);
        fin[m][1][j] += wt4[j] * (tmp[m][1][j] + cp1);
      }
    }
  }
  float cb0 = cnnb[h0], cb1 = cnnb[h0 + 16];
  #pragma unroll
  for (int m = 0; m < 2; ++m)
    #pragma unroll
    for (int j = 0; j < 4; ++j) {
      int r = wr * 32 + m * 16 + l4 * 4 + j;
      size_t o = ((size_t)(b * LL + l0 + r) << 7) + h0;
      out[o]      = fin[m][0][j] + cb0;
      out[o + 16] = fin[m][1][j] + cb1;
    }
}

extern "C" void kernel_launch(void* const* d_in, const int* in_sizes, int n_in,
                              void* d_out, int out_size, void* d_ws, size_t ws_size,
                              hipStream_t stream) {
  const float* emb  = (const float*)d_in[0];
  // d_in[1] masks: unused by reference
  const float* w1   = (const float*)d_in[2];
  const float* w1b  = (const float*)d_in[3];
  const float* w2   = (const float*)d_in[4];
  const float* w2b  = (const float*)d_in[5];
  const float* vw   = (const float*)d_in[6];
  // d_in[7] v_b: softmax-invariant, unused
  const float* cnn  = (const float*)d_in[8];
  const float* cnnb = (const float*)d_in[9];
  float* out = (float*)d_out;

  char* ws = (char*)d_ws;
  unsigned short* W12Bt = (unsigned short*)(ws);
  unsigned short* CwBt  = (unsigned short*)(ws + 65536);

  prep_kernel<<<704, 256, 0, stream>>>(w1, w2, cnn, W12Bt, CwBt);
  mega_kernel<<<512, 512, 69008, stream>>>(emb, W12Bt, CwBt, w1, w1b, w2, w2b,
                                           vw, cnn, cnnb, out);
}

// Round 6
// 130.789 us; speedup vs baseline: 1.1751x; 1.1751x over previous
//
#include <hip/hip_runtime.h>
#include <hip/hip_bf16.h>

// B=32 L=1024 D=128 H=128 W=9 F=137. Output f32 (32,1024,128).
// ws: W12Frag bf16[64tile][64lane][8] @0 (64KB)   — fragment-ordered w1d|w2d
//     CwFrag  bf16[288tile][64lane][8] @65536 (288KB) — fragment-ordered Cw per w
// Fragment order: tile covers (nTile 16cols, kk K/32); lane l holds B rows
// n=nTile*16+(l&15), k=kk*32+(l>>4)*8..+8 — so a wave's bf16x8 load is 1KB coalesced.
// mega: 512 blocks x 512 thr, 64 rows each. LDS 69008B (2 blocks/CU):
//   E   @0      uint4[80*16] : emb rows l0-4..l0+67 bf16, XOR-swizzled granules
//   Hs  @20480  bf16[2][80][128] : K-prescaled f,g; h XOR'd by ((row>>2)&3)<<4
//   pwL @61440  f32[9][128]; vwL @66048 f32[128]; wtT @66560 f32[9][68]
// tanh(x) = 1-2*rcp(1+exp2(K*x)), K=2*log2(e); Sum_h vw const cancels in softmax.

typedef __attribute__((ext_vector_type(8))) short bf16x8;
typedef __attribute__((ext_vector_type(4))) float f32x4;

#define LL 1024
#define TANHK 2.885390081777927f

__device__ __forceinline__ unsigned short f2bf(float f) {
  unsigned int u = __float_as_uint(f);
  u = u + 0x7FFFu + ((u >> 16) & 1u);   // RNE
  return (unsigned short)(u >> 16);
}
__device__ __forceinline__ float bf2f(unsigned short us) {
  return __uint_as_float(((unsigned int)us) << 16);
}

// ---------- prep: fragment-ordered bf16 weight copies ----------
__global__ __launch_bounds__(256) void prep_kernel(
    const float* __restrict__ w1, const float* __restrict__ w2,
    const float* __restrict__ cnn,
    unsigned short* __restrict__ W12Frag, unsigned short* __restrict__ CwFrag) {
  int gid = blockIdx.x * 256 + threadIdx.x;
  if (blockIdx.x < 128) {            // 32768: W12Frag, n = col of w1 (<128) / w2
    int d = gid >> 8, n = gid & 255;
    float v = (n < 128) ? w1[d * 128 + n] : w2[d * 128 + (n - 128)];
    int tile = (n >> 4) * 4 + (d >> 5);
    int lane = ((d >> 3) & 3) * 16 + (n & 15);
    W12Frag[(tile * 64 + lane) * 8 + (d & 7)] = f2bf(v);
  } else {                           // 147456 = 9*128*128: CwFrag
    int idx = gid - 32768;
    int h = idx & 127;
    int wd = idx >> 7;               // w*128 + d
    int w = wd >> 7, d = wd & 127;
    float v = cnn[(w * 137 + d) * 128 + h];
    int tile = (w * 8 + (h >> 4)) * 4 + (d >> 5);
    int lane = ((d >> 3) & 3) * 16 + (h & 15);
    CwFrag[(tile * 64 + lane) * 8 + (d & 7)] = f2bf(v);
  }
}

// ---------- mega ----------
__global__ __launch_bounds__(512, 4) void mega_kernel(
    const float* __restrict__ emb,
    const unsigned short* __restrict__ W12Frag,
    const unsigned short* __restrict__ CwFrag,
    const float* __restrict__ w1, const float* __restrict__ w1b,
    const float* __restrict__ w2, const float* __restrict__ w2b,
    const float* __restrict__ vw,
    const float* __restrict__ cnn, const float* __restrict__ cnnb,
    float* __restrict__ out) {
  extern __shared__ __align__(16) unsigned char smem[];
  uint4* E            = (uint4*)smem;                       // 20480
  unsigned short* Hs  = (unsigned short*)(smem + 20480);    // 40960
  float* pwL          = (float*)(smem + 61440);             // 4608
  float* vwL          = (float*)(smem + 66048);             // 512
  float* wtT          = (float*)(smem + 66560);             // 2448

  int tid = threadIdx.x;
  int bid = blockIdx.x;
  int b = bid >> 4, l0 = (bid & 15) << 6;
  int lane = tid & 63, wid = tid >> 6;
  int l15 = lane & 15, l4 = lane >> 4;
  const bf16x8* Wf = (const bf16x8*)W12Frag;
  const bf16x8* Cf = (const bf16x8*)CwFrag;

  // ---- phase 0: stage E (80 rows: 72 real + 8 zero-pad), pwL, vwL ----
  #pragma unroll
  for (int s = 0; s < 5; ++s) {
    int i = tid + s * 512;
    if (i < 1280) {
      int er = i >> 4, g = i & 15;
      int t = l0 + er - 4;
      uint4 v = {0u, 0u, 0u, 0u};
      if (er < 72 && t >= 0 && t < LL) {
        const float4* src = (const float4*)(emb + ((size_t)(b * LL + t) << 7) + g * 8);
        float4 x0 = src[0], x1 = src[1];
        v.x = f2bf(x0.x) | ((unsigned)f2bf(x0.y) << 16);
        v.y = f2bf(x0.z) | ((unsigned)f2bf(x0.w) << 16);
        v.z = f2bf(x1.x) | ((unsigned)f2bf(x1.y) << 16);
        v.w = f2bf(x1.z) | ((unsigned)f2bf(x1.w) << 16);
      }
      E[er * 16 + (g ^ (er & 7))] = v;
    } else if (i < 2432) {
      int idx = i - 1280;
      int w = idx >> 7, h = idx & 127;
      pwL[idx] = TANHK * (w2[(128 + w) * 128 + h] + w2b[h] +
                          w1[132 * 128 + h] + w1b[h]);
    } else {
      int h = i - 2432;
      vwL[h] = vw[h];
    }
  }
  __syncthreads();

  // ---- phase 2: Hs = K*(E @ w{1,2}d); 9 jobs (4 f-tiles rows 4..67, 5 g-tiles) ----
  const bf16x8* Eb = (const bf16x8*)E;
  #pragma unroll
  for (int it = 0; it < 2; ++it) {
    int job = it == 0 ? wid : 8;
    if (it == 0 || wid == 0) {
      int part = job >= 4;
      int er0 = part ? (job - 4) * 16 : 4 + job * 16;
      f32x4 acc[8];
      #pragma unroll
      for (int nn = 0; nn < 8; ++nn) acc[nn] = (f32x4){0.f, 0.f, 0.f, 0.f};
      #pragma unroll
      for (int kk = 0; kk < 4; ++kk) {
        int gk = kk * 4 + l4;
        int er = er0 + l15;
        bf16x8 aF = Eb[er * 16 + (gk ^ (er & 7))];
        #pragma unroll
        for (int nn = 0; nn < 8; ++nn) {
          bf16x8 bF = Wf[((part * 8 + nn) * 4 + kk) * 64 + lane];
          acc[nn] = __builtin_amdgcn_mfma_f32_16x16x32_bf16(aF, bF, acc[nn], 0, 0, 0);
        }
      }
      unsigned short* Hp = Hs + part * 10240;
      int hxor = (((er0 >> 2) + l4) & 3) << 4;   // == ((i2>>2)&3)<<4, row-derived
      #pragma unroll
      for (int nn = 0; nn < 8; ++nn)
        #pragma unroll
        for (int j = 0; j < 4; ++j) {
          int i2 = er0 + l4 * 4 + j;
          Hp[i2 * 128 + ((nn * 16 + l15) ^ hxor)] = f2bf(TANHK * acc[nn][j]);
        }
    }
  }
  __syncthreads();

  // ---- phase 3: scores + softmax; 4 rows per pass (16-lane groups) ----
  {
    int q = lane >> 4, u = lane & 15, u8 = u * 8;
    const unsigned short* Hs1 = Hs;
    const unsigned short* Hs2 = Hs + 10240;
    #pragma unroll
    for (int pass = 0; pass < 2; ++pass) {
      int r = wid * 8 + pass * 4 + q;
      int fi = r + 4;
      int fxor = ((fi >> 2) & 3) << 4;
      bf16x8 fraw = *(const bf16x8*)&Hs1[fi * 128 + (u8 ^ fxor)];
      float fr[8];
      #pragma unroll
      for (int j = 0; j < 8; ++j) fr[j] = bf2f((unsigned short)fraw[j]);
      f32x4 vr0 = *(const f32x4*)&vwL[u8];
      f32x4 vr1 = *(const f32x4*)&vwL[u8 + 4];
      float sc[9];
      #pragma unroll
      for (int w = 0; w < 9; ++w) {
        int gi = r + w;
        int gxor = ((gi >> 2) & 3) << 4;
        bf16x8 graw = *(const bf16x8*)&Hs2[gi * 128 + (u8 ^ gxor)];
        f32x4 pw0 = *(const f32x4*)&pwL[w * 128 + u8];
        f32x4 pw1 = *(const f32x4*)&pwL[w * 128 + u8 + 4];
        float a = 0.f;
        #pragma unroll
        for (int j = 0; j < 4; ++j) {
          float e = exp2f(fr[j] + bf2f((unsigned short)graw[j]) + pw0[j]);
          a = fmaf(vr0[j], __builtin_amdgcn_rcpf(1.f + e), a);
        }
        #pragma unroll
        for (int j = 0; j < 4; ++j) {
          float e = exp2f(fr[4 + j] + bf2f((unsigned short)graw[4 + j]) + pw1[j]);
          a = fmaf(vr1[j], __builtin_amdgcn_rcpf(1.f + e), a);
        }
        a += __shfl_xor(a, 1, 64);
        a += __shfl_xor(a, 2, 64);
        a += __shfl_xor(a, 4, 64);
        a += __shfl_xor(a, 8, 64);
        sc[w] = a;              // score = -2*sc (+const): min sc == max score
      }
      float mn = sc[0];
      #pragma unroll
      for (int w = 1; w < 9; ++w) mn = fminf(mn, sc[w]);
      float p[9], sum = 0.f;
      #pragma unroll
      for (int w = 0; w < 9; ++w) { p[w] = exp2f(TANHK * (mn - sc[w])); sum += p[w]; }
      float inv = __builtin_amdgcn_rcpf(sum);
      if (u < 9) {
        float wv = p[0];
        #pragma unroll
        for (int w = 1; w < 9; ++w) wv = (u == w) ? p[w] : wv;
        wtT[u * 68 + r] = wv * inv;
      }
    }
  }
  __syncthreads();

  // ---- phase 4: out-GEMM; A from E (unscaled), B coalesced frags from L2 ----
  int wr = wid >> 2, wc = wid & 3;     // 32 rows x 32 h per wave
  int h0 = wc * 32 + l15;
  f32x4 fin[2][2];
  #pragma unroll
  for (int m = 0; m < 2; ++m)
    #pragma unroll
    for (int n = 0; n < 2; ++n) fin[m][n] = (f32x4){0.f, 0.f, 0.f, 0.f};
  #pragma unroll
  for (int w = 0; w < 9; ++w) {
    f32x4 tmp[2][2];
    #pragma unroll
    for (int m = 0; m < 2; ++m)
      #pragma unroll
      for (int n = 0; n < 2; ++n) tmp[m][n] = (f32x4){0.f, 0.f, 0.f, 0.f};
    #pragma unroll
    for (int kk = 0; kk < 4; ++kk) {
      int gk = kk * 4 + l4;
      bf16x8 aF[2];
      #pragma unroll
      for (int m = 0; m < 2; ++m) {
        int er = wr * 32 + m * 16 + l15 + w;
        aF[m] = Eb[er * 16 + (gk ^ (er & 7))];
      }
      #pragma unroll
      for (int n = 0; n < 2; ++n) {
        bf16x8 bF = Cf[((w * 8 + wc * 2 + n) * 4 + kk) * 64 + lane];
        #pragma unroll
        for (int m = 0; m < 2; ++m)
          tmp[m][n] = __builtin_amdgcn_mfma_f32_16x16x32_bf16(aF[m], bF, tmp[m][n], 0, 0, 0);
      }
    }
    float cp0 = cnn[(w * 138 + 128) * 128 + h0];
    float cp1 = cnn[(w * 138 + 128) * 128 + h0 + 16];
    #pragma unroll
    for (int m = 0; m < 2; ++m) {
      f32x4 wt4 = *(const f32x4*)&wtT[w * 68 + wr * 32 + m * 16 + l4 * 4];
      #pragma unroll
      for (int j = 0; j < 4; ++j) {
        fin[m][0][j] += wt4[j] * (tmp[m][0][j] + cp0);
        fin[m][1][j] += wt4[j] * (tmp[m][1][j] + cp1);
      }
    }
  }
  float cb0 = cnnb[h0], cb1 = cnnb[h0 + 16];
  #pragma unroll
  for (int m = 0; m < 2; ++m)
    #pragma unroll
    for (int j = 0; j < 4; ++j) {
      int r = wr * 32 + m * 16 + l4 * 4 + j;
      size_t o = ((size_t)(b * LL + l0 + r) << 7) + h0;
      out[o]      = fin[m][0][j] + cb0;
      out[o + 16] = fin[m][1][j] + cb1;
    }
}

extern "C" void kernel_launch(void* const* d_in, const int* in_sizes, int n_in,
                              void* d_out, int out_size, void* d_ws, size_t ws_size,
                              hipStream_t stream) {
  const float* emb  = (const float*)d_in[0];
  // d_in[1] masks: unused by reference
  const float* w1   = (const float*)d_in[2];
  const float* w1b  = (const float*)d_in[3];
  const float* w2   = (const float*)d_in[4];
  const float* w2b  = (const float*)d_in[5];
  const float* vw   = (const float*)d_in[6];
  // d_in[7] v_b: softmax-invariant, unused
  const float* cnn  = (const float*)d_in[8];
  const float* cnnb = (const float*)d_in[9];
  float* out = (float*)d_out;

  char* ws = (char*)d_ws;
  unsigned short* W12Frag = (unsigned short*)(ws);
  unsigned short* CwFrag  = (unsigned short*)(ws + 65536);

  prep_kernel<<<704, 256, 0, stream>>>(w1, w2, cnn, W12Frag, CwFrag);
  mega_kernel<<<512, 512, 69008, stream>>>(emb, W12Frag, CwFrag, w1, w1b, w2, w2b,
                                           vw, cnn, cnnb, out);
}